// Round 6
// baseline (170.180 us; speedup 1.0000x reference)
//
#include <hip/hip_runtime.h>
#include <hip/hip_bf16.h>

typedef __bf16 bf16;
typedef bf16 bf16x8 __attribute__((ext_vector_type(8)));
typedef bf16 bf16x4 __attribute__((ext_vector_type(4)));
typedef float f32x4 __attribute__((ext_vector_type(4)));

constexpr int B = 4, C = 512, L = 2048, H = 8, DH = 64;
constexpr int BL = B * L;        // 8192
constexpr int BH = B * H;        // 32
constexpr int N_QKV = 3 * C;     // 1536
constexpr float QSCALE = 0.125f * 1.44269504088896f;  // DH^-0.5 * log2(e), folded into Q
constexpr float EPS = 1e-5f;

// ---- workspace layout (bytes) ----
constexpr size_t SZ = (size_t)BL * C;                 // 4,194,304 elems
constexpr size_t OFF_HN    = 0;                       // SZ bf16
constexpr size_t OFF_WQKV  = OFF_HN    + SZ * 2;      // N_QKV*C bf16
constexpr size_t OFF_WPROJ = OFF_WQKV  + (size_t)N_QKV * C * 2;
constexpr size_t OFF_Q     = OFF_WPROJ + (size_t)C * C * 2;
constexpr size_t OFF_K     = OFF_Q     + SZ * 2;
constexpr size_t OFF_V     = OFF_K     + SZ * 2;      // V stored TRANSPOSED [B,H,DH,L]
constexpr size_t OFF_O     = OFF_V     + SZ * 2;      // (unused)
constexpr size_t OFF_STATS = OFF_O     + SZ * 2;      // (unused)
constexpr size_t OFF_OPART = OFF_STATS + (size_t)BL * 2 * 4;   // [2][BH][L][DH] bf16
constexpr size_t OFF_ML    = OFF_OPART + (size_t)2 * BH * L * DH * 2;  // [2][BH][L] float

__device__ __forceinline__ bf16x8 ld8(const bf16* p) {
  return *(const bf16x8*)p;
}

__device__ __forceinline__ void gll16(const bf16* g, bf16* l) {
  __builtin_amdgcn_global_load_lds(
      (const __attribute__((address_space(1))) unsigned int*)(const void*)g,
      (__attribute__((address_space(3))) unsigned int*)(void*)l, 16, 0, 0);
}

// bias-rounded bf16 pack: (hi16(a+0x8000) low | hi16(b+0x8000) high)
__device__ __forceinline__ unsigned pack_bf16(float a, float b) {
  unsigned ua = __builtin_bit_cast(unsigned, a) + 0x8000u;
  unsigned ub = __builtin_bit_cast(unsigned, b) + 0x8000u;
  return __builtin_amdgcn_perm(ub, ua, 0x07060302u);
}
__device__ __forceinline__ float bf_lo(unsigned u) { return __builtin_bit_cast(float, u << 16); }
__device__ __forceinline__ float bf_hi(unsigned u) { return __builtin_bit_cast(float, u & 0xFFFF0000u); }

// ---------------- fused LayerNorm + weight conversion ----------------
// grid: B * (L/32) = 256 blocks, 1024 threads. x tile (512 c x 32 l fp32) in LDS.
// Tail: converts wqkv (3 strided passes) + wproj (1 pass) to bf16 — replaces k_convert_w.
__global__ __launch_bounds__(1024) void k_ln(const float* __restrict__ x,
                                             const float* __restrict__ gamma,
                                             const float* __restrict__ beta,
                                             const float* __restrict__ wqkv,
                                             const float* __restrict__ wproj,
                                             bf16* __restrict__ hn,
                                             bf16* __restrict__ wqkv_b,
                                             bf16* __restrict__ wproj_b) {
  int blk = blockIdx.x;
  int b = blk >> 6;             // 64 l-tiles per batch
  int l0 = (blk & 63) << 5;
  int t = threadIdx.x;
  int ll = t & 31;
  int cg = t >> 5;              // 0..31, each group covers 16 c
  __shared__ float tile[512][33];
  __shared__ float sh_s[32][33];
  __shared__ float sh_q[32][33];
  __shared__ float mu_s[32], rs_s[32];
  const float* xp = x + ((size_t)b * C) * L + l0;
  float s = 0.f, ss = 0.f;
#pragma unroll
  for (int r = 0; r < 16; ++r) {
    int c = cg * 16 + r;
    float v = xp[(size_t)c * L + ll];
    tile[c][ll] = v;
    s += v; ss += v * v;
  }
  sh_s[cg][ll] = s; sh_q[cg][ll] = ss;
  __syncthreads();
  if (t < 32) {
    float ts = 0.f, tq = 0.f;
#pragma unroll
    for (int i = 0; i < 32; ++i) { ts += sh_s[i][t]; tq += sh_q[i][t]; }
    float mu = ts * (1.0f / C);
    float var = tq * (1.0f / C) - mu * mu;
    mu_s[t] = mu;
    rs_s[t] = rsqrtf(var + EPS);
  }
  __syncthreads();
  int c2 = (t & 255) * 2;
  int lgrp = t >> 8;
  float g0 = gamma[c2], g1 = gamma[c2 + 1];
  float b0 = beta[c2],  b1 = beta[c2 + 1];
#pragma unroll
  for (int it = 0; it < 8; ++it) {
    int l = lgrp * 8 + it;
    float mu = mu_s[l], rstd = rs_s[l];
    float v0 = (tile[c2][l]     - mu) * rstd * g0 + b0;
    float v1 = (tile[c2 + 1][l] - mu) * rstd * g1 + b1;
    *(unsigned*)&hn[(size_t)(b * L + l0 + l) * C + c2] = pack_bf16(v0, v1);
  }
  // fused weight conversion: 262144 threads total; wqkv = 3x262144, wproj = 1x262144
  int gid = blk * 1024 + t;
#pragma unroll
  for (int i = 0; i < 3; ++i)
    wqkv_b[gid + i * 262144] = (bf16)wqkv[gid + i * 262144];
  wproj_b[gid] = (bf16)wproj[gid];
}

// ---------------- QKV GEMM: 128x128 tile, global_load_lds, swizzled LDS ----------------
// v15: 1D grid + XCD-grouped decode. Old 2D grid (64 mt, 12 nt) dispatched mt-fastest:
// the 12 nt-blocks sharing one 128 KB hn A-tile were 64 slots apart -> different XCD,
// different time -> hn refetched ~12x (~96 MB), wqkv panels refetched similarly.
// Same mechanism as attn v10->v11 (FETCH 157->75 MB, idx%8 -> XCD verified on this HW).
// New: xcd = mt&7; within an XCD, nt is fastest -> all 12 nt of an mt adjacent + same L2.
// Concurrent set/XCD: 8 A-tiles x 128 KB + wqkv 1.5 MB = 2.5 MB < 4 MB L2.
__global__ __launch_bounds__(256) void k_gemm_qkv(const bf16* __restrict__ hn,
                                                  const bf16* __restrict__ wq,
                                                  const float* __restrict__ bq,
                                                  bf16* __restrict__ qg,
                                                  bf16* __restrict__ kg,
                                                  bf16* __restrict__ vg) {
  int i0 = blockIdx.x;               // 768 = 8 XCD x 96 slots
  int xcd = i0 & 7, slot = i0 >> 3;
  int g = slot / 12, nt = slot - g * 12;  // g in [0,8)
  int mt = g * 8 + xcd;
  int m0 = mt << 7, n0 = nt << 7;
  int t = threadIdx.x, lane = t & 63, w = t >> 6;
  int mw = w >> 1, nw = w & 1;
  int q4 = lane >> 4, c16 = lane & 15;
  __shared__ __align__(16) char smem[36864];
  bf16* As = (bf16*)smem;            // [128][64] 16B-chunk XOR swizzled
  bf16* Bs = (bf16*)(smem + 16384);

  int goff[4], ldsoff[4];
#pragma unroll
  for (int p = 0; p < 4; ++p) {
    int idx = (p * 4 + w) * 64 + lane;
    int row = idx >> 3, s0 = idx & 7;
    goff[p] = row * C + (s0 ^ (row & 7)) * 8;
    ldsoff[p] = (p * 4 + w) * 512;
  }

  f32x4 acc[4][4];
#pragma unroll
  for (int mi = 0; mi < 4; ++mi)
#pragma unroll
    for (int ni = 0; ni < 4; ++ni) acc[mi][ni] = (f32x4){0.f, 0.f, 0.f, 0.f};

  const bf16* ap = hn + (size_t)m0 * C;
  const bf16* bp = wq + (size_t)n0 * C;
  for (int k0 = 0; k0 < C; k0 += 64) {
    __syncthreads();
#pragma unroll
    for (int p = 0; p < 4; ++p) {
      gll16(ap + k0 + goff[p], As + ldsoff[p]);
      gll16(bp + k0 + goff[p], Bs + ldsoff[p]);
    }
    __syncthreads();
#pragma unroll
    for (int kk2 = 0; kk2 < 2; ++kk2) {
      bf16x8 af[4], bfr[4];
#pragma unroll
      for (int mi = 0; mi < 4; ++mi) {
        int row = mw * 64 + mi * 16 + c16;
        af[mi] = ld8(As + row * 64 + ((kk2 * 4 + q4) ^ (row & 7)) * 8);
      }
#pragma unroll
      for (int ni = 0; ni < 4; ++ni) {
        int row = nw * 64 + ni * 16 + c16;
        bfr[ni] = ld8(Bs + row * 64 + ((kk2 * 4 + q4) ^ (row & 7)) * 8);
      }
#pragma unroll
      for (int mi = 0; mi < 4; ++mi)
#pragma unroll
        for (int ni = 0; ni < 4; ++ni)
          acc[mi][ni] = __builtin_amdgcn_mfma_f32_16x16x32_bf16(af[mi], bfr[ni], acc[mi][ni], 0, 0, 0);
    }
  }
  __syncthreads();

  int i = nt >> 2;                    // 0=q 1=k 2=v
  int h = ((nt & 3) << 1) + nw;
  int b = m0 >> 11;
  int l0 = (m0 & (L - 1)) + mw * 64;
  float bias[4];
#pragma unroll
  for (int ni = 0; ni < 4; ++ni) bias[ni] = bq[n0 + nw * 64 + ni * 16 + c16];
  bf16* Os = (bf16*)(smem + w * 9216);  // per-wave [64][72]

  if (i == 2) {
#pragma unroll
    for (int mi = 0; mi < 4; ++mi)
#pragma unroll
      for (int ni = 0; ni < 4; ++ni) {
        bf16x4 pk;
#pragma unroll
        for (int r = 0; r < 4; ++r) pk[r] = (bf16)(acc[mi][ni][r] + bias[ni]);
        *(bf16x4*)&Os[(ni * 16 + c16) * 72 + mi * 16 + q4 * 4] = pk;
      }
    __syncthreads();
    const bf16* src = Os + lane * 72;
    bf16* dst = vg + ((size_t)((b * H + h) * DH + lane)) * L + l0;
#pragma unroll
    for (int s = 0; s < 8; ++s)
      *(uint4*)(dst + s * 8) = *(const uint4*)(src + s * 8);
  } else {
    float sc = (i == 0) ? QSCALE : 1.0f;
#pragma unroll
    for (int mi = 0; mi < 4; ++mi)
#pragma unroll
      for (int ni = 0; ni < 4; ++ni)
#pragma unroll
        for (int r = 0; r < 4; ++r)
          Os[(mi * 16 + q4 * 4 + r) * 72 + ni * 16 + c16] = (bf16)((acc[mi][ni][r] + bias[ni]) * sc);
    __syncthreads();
    bf16* dst0 = (i == 0) ? qg : kg;
    const bf16* src = Os + lane * 72;
    bf16* dst = dst0 + ((size_t)((b * H + h) * L + l0 + lane)) * DH;
#pragma unroll
    for (int s = 0; s < 8; ++s)
      *(uint4*)(dst + s * 8) = *(const uint4*)(src + s * 8);
  }
}

// ---------------- flash attention v14: v12 skeleton + permlane P-transpose (no Ps LDS) ----------------
// PLATEAU (parked): v6 / v12 / v14 — three different structures — all 53.5±0.5 µs.
// v14 has bank-conflicts 0, FETCH 12 MB, LDS 32 KB; compute-phase latency in lockstep
// convoy is the residual. Occupancy↑ (v13) hurt, DS↓ (v14) neutral, pipelining (v12)
// neutral. Leave as-is; remaining pipeline time lives in the GEMMs.
__global__ __launch_bounds__(256, 4) void k_attn(const bf16* __restrict__ qg,
                                                 const bf16* __restrict__ kg,
                                                 const bf16* __restrict__ vt,
                                                 bf16* __restrict__ opart,
                                                 float* __restrict__ lsum) {
  // XCD-aware decode: x = XCD, 128 slots per XCD cover bh ∈ {x, x+8, x+16, x+24};
  // inner js-major: consecutive slots share js (same K/V stream) for convoy sharing.
  int i0 = blockIdx.x;
  int x = i0 & 7, slot = i0 >> 3;
  int bh = ((slot >> 5) << 3) + x;   // (slot/32)*8 + x  ∈ [0,32)
  int inner = slot & 31;
  int js = inner >> 4;
  int qt = inner & 15;
  int t = threadIdx.x, lane = t & 63, w = t >> 6;  // w: 0..3
  int q4 = lane >> 4, c16 = lane & 15;
  __shared__ __align__(16) bf16 Ks[2][64][64];    // 16B-chunk XOR swizzled, double-buffered
  __shared__ __align__(16) bf16 Vts[2][64][64];   // [d][j], same swizzle, double-buffered
  const bf16* qptr  = qg + ((size_t)bh * L + qt * 128 + w * 32) * DH;
  const bf16* kptr  = kg + (size_t)bh * L * DH;
  const bf16* vtptr = vt + (size_t)bh * DH * L;

  int ksoff[2], vsoff[2];
#pragma unroll
  for (int p = 0; p < 2; ++p) {
    int ci = p * 256 + w * 64 + lane;
    int row = ci >> 3, s0 = ci & 7;
    int ch = s0 ^ (row & 7);
    ksoff[p] = row * DH + ch * 8;
    vsoff[p] = row * L + ch * 8;
  }
  int sw = c16 & 7;

  bf16x8 qf[2][2];
#pragma unroll
  for (int qb = 0; qb < 2; ++qb)
#pragma unroll
    for (int kk2 = 0; kk2 < 2; ++kk2)
      qf[qb][kk2] = ld8(&qptr[(size_t)(qb * 16 + c16) * DH + kk2 * 32 + q4 * 8]);

  f32x4 o_acc[2][4];                 // O^T: col=q(c16), rows d = db*16+q4*4+r
  float l_i[2] = {0.f, 0.f};
#pragma unroll
  for (int qb = 0; qb < 2; ++qb)
#pragma unroll
    for (int db = 0; db < 4; ++db) o_acc[qb][db] = (f32x4){0.f, 0.f, 0.f, 0.f};

  // prologue: stage j-tile 0 into buffer 0, full drain + barrier (iter 0 reads it)
  {
    int j0 = js * 1024;
#pragma unroll
    for (int p = 0; p < 2; ++p) {
      gll16(kptr + (size_t)j0 * DH + ksoff[p], &Ks[0][0][0]  + (p * 4 + w) * 512);
      gll16(vtptr + j0 + vsoff[p],             &Vts[0][0][0] + (p * 4 + w) * 512);
    }
  }
  asm volatile("s_waitcnt vmcnt(0)" ::: "memory");
  __builtin_amdgcn_s_barrier();
  __builtin_amdgcn_sched_barrier(0);

  for (int it = 0; it < 16; ++it) {
    int cur = it & 1;
    // issue next-tile stage FIRST: these loads fly across the whole compute phase
    if (it < 15) {
      int j1 = js * 1024 + (it + 1) * 64;
#pragma unroll
      for (int p = 0; p < 2; ++p) {
        gll16(kptr + (size_t)j1 * DH + ksoff[p], &Ks[cur ^ 1][0][0]  + (p * 4 + w) * 512);
        gll16(vtptr + j1 + vsoff[p],             &Vts[cur ^ 1][0][0] + (p * 4 + w) * 512);
      }
    }
    const bf16* KsC = &Ks[cur][0][0];
    const bf16* VsC = &Vts[cur][0][0];

    // S^T[j][q]: A = K (rows=j), B = Q (rows=q)
    f32x4 s[2][4];
#pragma unroll
    for (int qb = 0; qb < 2; ++qb)
#pragma unroll
      for (int jb = 0; jb < 4; ++jb) s[qb][jb] = (f32x4){0.f, 0.f, 0.f, 0.f};
#pragma unroll
    for (int kk2 = 0; kk2 < 2; ++kk2) {
      int choff = ((kk2 * 4 + q4) ^ sw) * 8;
#pragma unroll
      for (int jb = 0; jb < 4; ++jb) {
        bf16x8 kf = ld8(KsC + (jb * 16 + c16) * 64 + choff);
        s[0][jb] = __builtin_amdgcn_mfma_f32_16x16x32_bf16(kf, qf[0][kk2], s[0][jb], 0, 0, 0);
        s[1][jb] = __builtin_amdgcn_mfma_f32_16x16x32_bf16(kf, qf[1][kk2], s[1][jb], 0, 0, 0);
      }
    }

    // no-max softmax: P = exp2(S)
#pragma unroll
    for (int qb = 0; qb < 2; ++qb) {
      float rs = 0.f;
#pragma unroll
      for (int jb = 0; jb < 4; ++jb)
#pragma unroll
        for (int r = 0; r < 4; ++r) {
          float p_ = __builtin_amdgcn_exp2f(s[qb][jb][r]);
          s[qb][jb][r] = p_;
          rs += p_;
        }
      l_i[qb] += rs;
    }

    // V^T A-fragments (shared across both qb)
    bf16x8 vf[2][4];
#pragma unroll
    for (int kk2 = 0; kk2 < 2; ++kk2) {
      int choff = ((kk2 * 4 + q4) ^ sw) * 8;
#pragma unroll
      for (int db = 0; db < 4; ++db)
        vf[kk2][db] = ld8(VsC + (db * 16 + c16) * 64 + choff);
    }

    // O^T += V^T P^T : P B-fragment via in-register quad-group transpose (VALU, no LDS).
#pragma unroll
    for (int qb = 0; qb < 2; ++qb) {
#pragma unroll
      for (int kk2 = 0; kk2 < 2; ++kk2) {
        unsigned a = pack_bf16(s[qb][2 * kk2][0],     s[qb][2 * kk2][1]);
        unsigned b = pack_bf16(s[qb][2 * kk2][2],     s[qb][2 * kk2][3]);
        unsigned c = pack_bf16(s[qb][2 * kk2 + 1][0], s[qb][2 * kk2 + 1][1]);
        unsigned d = pack_bf16(s[qb][2 * kk2 + 1][2], s[qb][2 * kk2 + 1][3]);
        asm("v_permlane32_swap_b32 %0, %1" : "+v"(a), "+v"(c));
        asm("v_permlane32_swap_b32 %0, %1" : "+v"(b), "+v"(d));
        asm("v_permlane16_swap_b32 %0, %1" : "+v"(a), "+v"(c));
        asm("v_permlane16_swap_b32 %0, %1" : "+v"(b), "+v"(d));
        uint4 pu = {a, b, c, d};     // pf u32s: j {+0,+1},{+2,+3},{+4,+5},{+6,+7}
        bf16x8 pf = __builtin_bit_cast(bf16x8, pu);
#pragma unroll
        for (int db = 0; db < 4; ++db)
          o_acc[qb][db] = __builtin_amdgcn_mfma_f32_16x16x32_bf16(vf[kk2][db], pf, o_acc[qb][db], 0, 0, 0);
      }
    }

    // full drain at iter END: prefetch had the whole compute phase to land ->
    // wait ~free when L2-resident; global re-sync every iter -> convoy preserved.
    asm volatile("s_waitcnt vmcnt(0)" ::: "memory");
    __builtin_amdgcn_s_barrier();
    __builtin_amdgcn_sched_barrier(0);
  }

  // epilogue: finish l across quads, store raw partials + l
#pragma unroll
  for (int qb = 0; qb < 2; ++qb) {
    float lf = l_i[qb];
    lf += __shfl_xor(lf, 16, 64);
    lf += __shfl_xor(lf, 32, 64);
    int q = qt * 128 + w * 32 + qb * 16 + c16;
    bf16* op = opart + (((size_t)js * BH + bh) * L + q) * DH;
#pragma unroll
    for (int db = 0; db < 4; ++db) {
      uint2 pk;
      pk.x = pack_bf16(o_acc[qb][db][0], o_acc[qb][db][1]);
      pk.y = pack_bf16(o_acc[qb][db][2], o_acc[qb][db][3]);
      *(uint2*)&op[db * 16 + q4 * 4] = pk;
    }
    if (q4 == 0) lsum[((size_t)js * BH + bh) * L + q] = lf;
  }
}

// ---------------- proj GEMM with inline split-j merge + bias + residual ----------------
// v15: 1D grid + XCD-grouped decode. Old 2D grid (128 mt, 8 nt) dispatched mt-fastest:
// the 8 nt-blocks sharing one opart A-strip were 128 slots apart -> opart refetched ~8x
// (~128 MB). New: xcd = mt&7, nt fastest within XCD -> A-strip shared in L2.
// Concurrent set/XCD: 16 A-strips x 128 KB + wp 0.5 MB = 2.5 MB < 4 MB L2.
__global__ __launch_bounds__(256) void k_gemm_proj(const bf16* __restrict__ opart,
                                                   const float* __restrict__ lsum,
                                                   const bf16* __restrict__ wp,
                                                   const float* __restrict__ bp,
                                                   const float* __restrict__ x,
                                                   float* __restrict__ out) {
  int i0 = blockIdx.x;               // 1024 = 8 XCD x 128 slots
  int xcd = i0 & 7, slot = i0 >> 3;
  int nt = slot & 7, g = slot >> 3;  // g in [0,16)
  int mt = g * 8 + xcd;
  int m0 = mt << 6, n0 = nt << 6;
  int t = threadIdx.x;
  int lane = t & 63, w = t >> 6;
  int q4 = lane >> 4, c16 = lane & 15;
  __shared__ __align__(16) bf16 As[64][72];
  __shared__ __align__(16) bf16 Bs[64][72];
  __shared__ float Ot[64][65];
  __shared__ float invs[64][9];
  int b = m0 >> 11, q0 = m0 & (L - 1);
  for (int i = t; i < 512; i += 256) {
    int row = i >> 3, h = i & 7;
    int bhh = b * 8 + h;
    float l0v = lsum[(size_t)bhh * L + q0 + row];
    float l1v = lsum[((size_t)BH + bhh) * L + q0 + row];
    invs[row][h] = 1.0f / (l0v + l1v);
  }
  f32x4 acc[4];
#pragma unroll
  for (int nb = 0; nb < 4; ++nb) acc[nb] = (f32x4){0.f, 0.f, 0.f, 0.f};

  for (int k0 = 0; k0 < C; k0 += 64) {
    __syncthreads();
    int h = k0 >> 6;
    const bf16* ap0 = opart + ((size_t)(b * 8 + h) * L + q0) * 64;
    const bf16* ap1 = opart + ((size_t)(BH + b * 8 + h) * L + q0) * 64;
#pragma unroll
    for (int p = 0; p < 2; ++p) {
      int idx = p * 256 + t;
      int row = idx >> 3, ch = idx & 7;
      uint4 u0 = *(const uint4*)(ap0 + (size_t)row * 64 + ch * 8);
      uint4 u1 = *(const uint4*)(ap1 + (size_t)row * 64 + ch * 8);
      float inv = invs[row][h];
      unsigned* pu0 = (unsigned*)&u0;
      unsigned* pu1 = (unsigned*)&u1;
      uint4 m;
      unsigned* pm = (unsigned*)&m;
#pragma unroll
      for (int k = 0; k < 4; ++k)
        pm[k] = pack_bf16((bf_lo(pu0[k]) + bf_lo(pu1[k])) * inv,
                          (bf_hi(pu0[k]) + bf_hi(pu1[k])) * inv);
      *(uint4*)&As[row][ch * 8] = m;
      *(bf16x8*)&Bs[row][ch * 8] = ld8(&wp[(size_t)(n0 + row) * C + k0 + ch * 8]);
    }
    __syncthreads();
#pragma unroll
    for (int kk = 0; kk < 64; kk += 32) {
      bf16x8 a = ld8(&As[w * 16 + c16][kk + q4 * 8]);
#pragma unroll
      for (int nb = 0; nb < 4; ++nb) {
        bf16x8 bfr = ld8(&Bs[nb * 16 + c16][kk + q4 * 8]);
        acc[nb] = __builtin_amdgcn_mfma_f32_16x16x32_bf16(a, bfr, acc[nb], 0, 0, 0);
      }
    }
  }
  __syncthreads();
#pragma unroll
  for (int nb = 0; nb < 4; ++nb)
#pragma unroll
    for (int r = 0; r < 4; ++r)
      Ot[w * 16 + q4 * 4 + r][nb * 16 + c16] = acc[nb][r];
  __syncthreads();
#pragma unroll
  for (int r = 0; r < 16; ++r) {
    int cl = w * 16 + r;
    int c = n0 + cl;
    size_t idx = (size_t)(b * C + c) * L + q0 + lane;
    out[idx] = Ot[lane][cl] + bp[c] + x[idx];
  }
}

extern "C" void kernel_launch(void* const* d_in, const int* in_sizes, int n_in,
                              void* d_out, int out_size, void* d_ws, size_t ws_size,
                              hipStream_t stream) {
  const float* x     = (const float*)d_in[0];
  const float* gamma = (const float*)d_in[1];
  const float* beta  = (const float*)d_in[2];
  const float* wqkv  = (const float*)d_in[3];
  const float* bqkv  = (const float*)d_in[4];
  const float* wproj = (const float*)d_in[5];
  const float* bproj = (const float*)d_in[6];
  float* out = (float*)d_out;
  char* ws = (char*)d_ws;
  bf16* hn  = (bf16*)(ws + OFF_HN);
  bf16* wqb = (bf16*)(ws + OFF_WQKV);
  bf16* wpb = (bf16*)(ws + OFF_WPROJ);
  bf16* qbp = (bf16*)(ws + OFF_Q);
  bf16* kbp = (bf16*)(ws + OFF_K);
  bf16* vbp = (bf16*)(ws + OFF_V);
  bf16* opart = (bf16*)(ws + OFF_OPART);
  float* lsum = (float*)(ws + OFF_ML);

  hipLaunchKernelGGL(k_ln, dim3(B * (L / 32)), dim3(1024), 0, stream,
                     x, gamma, beta, wqkv, wproj, hn, wqb, wpb);
  hipLaunchKernelGGL(k_gemm_qkv, dim3((BL / 128) * (N_QKV / 128)), dim3(256), 0, stream,
                     hn, wqb, bqkv, qbp, kbp, vbp);
  hipLaunchKernelGGL(k_attn, dim3(B * H * (L / 128) * 2), dim3(256), 0, stream,
                     qbp, kbp, vbp, opart, lsum);
  hipLaunchKernelGGL(k_gemm_proj, dim3((BL / 64) * (C / 64)), dim3(256), 0, stream,
                     opart, lsum, wpb, bproj, x, out);
}

// Round 7
// 168.747 us; speedup vs baseline: 1.0085x; 1.0085x over previous
//
#include <hip/hip_runtime.h>
#include <hip/hip_bf16.h>

typedef __bf16 bf16;
typedef bf16 bf16x8 __attribute__((ext_vector_type(8)));
typedef bf16 bf16x4 __attribute__((ext_vector_type(4)));
typedef float f32x4 __attribute__((ext_vector_type(4)));

constexpr int B = 4, C = 512, L = 2048, H = 8, DH = 64;
constexpr int BL = B * L;        // 8192
constexpr int BH = B * H;        // 32
constexpr int N_QKV = 3 * C;     // 1536
constexpr float QSCALE = 0.125f * 1.44269504088896f;  // DH^-0.5 * log2(e), folded into Q
constexpr float EPS = 1e-5f;

// ---- workspace layout (bytes) ----
constexpr size_t SZ = (size_t)BL * C;                 // 4,194,304 elems
constexpr size_t OFF_HN    = 0;                       // SZ bf16
constexpr size_t OFF_WQKV  = OFF_HN    + SZ * 2;      // N_QKV*C bf16
constexpr size_t OFF_WPROJ = OFF_WQKV  + (size_t)N_QKV * C * 2;
constexpr size_t OFF_Q     = OFF_WPROJ + (size_t)C * C * 2;
constexpr size_t OFF_K     = OFF_Q     + SZ * 2;
constexpr size_t OFF_V     = OFF_K     + SZ * 2;      // V stored TRANSPOSED [B,H,DH,L]
constexpr size_t OFF_O     = OFF_V     + SZ * 2;      // (unused)
constexpr size_t OFF_STATS = OFF_O     + SZ * 2;      // (unused)
constexpr size_t OFF_OPART = OFF_STATS + (size_t)BL * 2 * 4;   // [2][BH][L][DH] bf16
constexpr size_t OFF_ML    = OFF_OPART + (size_t)2 * BH * L * DH * 2;  // [2][BH][L] float

__device__ __forceinline__ bf16x8 ld8(const bf16* p) {
  return *(const bf16x8*)p;
}

__device__ __forceinline__ void gll16(const bf16* g, bf16* l) {
  __builtin_amdgcn_global_load_lds(
      (const __attribute__((address_space(1))) unsigned int*)(const void*)g,
      (__attribute__((address_space(3))) unsigned int*)(void*)l, 16, 0, 0);
}

// bias-rounded bf16 pack: (hi16(a+0x8000) low | hi16(b+0x8000) high)
__device__ __forceinline__ unsigned pack_bf16(float a, float b) {
  unsigned ua = __builtin_bit_cast(unsigned, a) + 0x8000u;
  unsigned ub = __builtin_bit_cast(unsigned, b) + 0x8000u;
  return __builtin_amdgcn_perm(ub, ua, 0x07060302u);
}
__device__ __forceinline__ float bf_lo(unsigned u) { return __builtin_bit_cast(float, u << 16); }
__device__ __forceinline__ float bf_hi(unsigned u) { return __builtin_bit_cast(float, u & 0xFFFF0000u); }

// ---------------- fused LayerNorm + weight conversion ----------------
// grid: B * (L/32) = 256 blocks, 1024 threads. x tile (512 c x 32 l fp32) in LDS.
// Tail: converts wqkv (3 strided passes) + wproj (1 pass) to bf16 — replaces k_convert_w.
__global__ __launch_bounds__(1024) void k_ln(const float* __restrict__ x,
                                             const float* __restrict__ gamma,
                                             const float* __restrict__ beta,
                                             const float* __restrict__ wqkv,
                                             const float* __restrict__ wproj,
                                             bf16* __restrict__ hn,
                                             bf16* __restrict__ wqkv_b,
                                             bf16* __restrict__ wproj_b) {
  int blk = blockIdx.x;
  int b = blk >> 6;             // 64 l-tiles per batch
  int l0 = (blk & 63) << 5;
  int t = threadIdx.x;
  int ll = t & 31;
  int cg = t >> 5;              // 0..31, each group covers 16 c
  __shared__ float tile[512][33];
  __shared__ float sh_s[32][33];
  __shared__ float sh_q[32][33];
  __shared__ float mu_s[32], rs_s[32];
  const float* xp = x + ((size_t)b * C) * L + l0;
  float s = 0.f, ss = 0.f;
#pragma unroll
  for (int r = 0; r < 16; ++r) {
    int c = cg * 16 + r;
    float v = xp[(size_t)c * L + ll];
    tile[c][ll] = v;
    s += v; ss += v * v;
  }
  sh_s[cg][ll] = s; sh_q[cg][ll] = ss;
  __syncthreads();
  if (t < 32) {
    float ts = 0.f, tq = 0.f;
#pragma unroll
    for (int i = 0; i < 32; ++i) { ts += sh_s[i][t]; tq += sh_q[i][t]; }
    float mu = ts * (1.0f / C);
    float var = tq * (1.0f / C) - mu * mu;
    mu_s[t] = mu;
    rs_s[t] = rsqrtf(var + EPS);
  }
  __syncthreads();
  int c2 = (t & 255) * 2;
  int lgrp = t >> 8;
  float g0 = gamma[c2], g1 = gamma[c2 + 1];
  float b0 = beta[c2],  b1 = beta[c2 + 1];
#pragma unroll
  for (int it = 0; it < 8; ++it) {
    int l = lgrp * 8 + it;
    float mu = mu_s[l], rstd = rs_s[l];
    float v0 = (tile[c2][l]     - mu) * rstd * g0 + b0;
    float v1 = (tile[c2 + 1][l] - mu) * rstd * g1 + b1;
    *(unsigned*)&hn[(size_t)(b * L + l0 + l) * C + c2] = pack_bf16(v0, v1);
  }
  // fused weight conversion: 262144 threads total; wqkv = 3x262144, wproj = 1x262144
  int gid = blk * 1024 + t;
#pragma unroll
  for (int i = 0; i < 3; ++i)
    wqkv_b[gid + i * 262144] = (bf16)wqkv[gid + i * 262144];
  wproj_b[gid] = (bf16)wproj[gid];
}

// ---------------- QKV GEMM v16: BK=32 rotated-drain double-buffer ----------------
// Evidence: total-minus-attn stable at ~117 µs across 7 rounds, immune to grid swizzle
// (v15 neutral) -> not refetch-bound. Same disease as attn's measured state: lockstep
// stage->drain->compute exposes full load latency each k-step (~50% issue occupancy).
// Unlike attn, the GEMM has 16 INDEPENDENT acc chains/wave -> pipelining can bite.
// v16: BK 64->32, dbuf (2 bufs x 8 KB x 2 mats = 32 KB, same 4 blocks/CU — avoids the
// m132 occupancy trap of BK=128). Rotated drain: issue 4 gll16 for step k+1 at top,
// 16 MFMA on step k (~1000 cy/CU >= L2 latency), __syncthreads() drain at bottom.
// 4-chunk swizzle key (row+(row>>2))&3: fragment-read's 16 rows hit each 16B slot
// exactly 2x -> conflict-free (m136: 2-way is free).
__global__ __launch_bounds__(256) void k_gemm_qkv(const bf16* __restrict__ hn,
                                                  const bf16* __restrict__ wq,
                                                  const float* __restrict__ bq,
                                                  bf16* __restrict__ qg,
                                                  bf16* __restrict__ kg,
                                                  bf16* __restrict__ vg) {
  int i0 = blockIdx.x;               // 768 = 8 XCD x 96 slots (v15 XCD grouping kept)
  int xcd = i0 & 7, slot = i0 >> 3;
  int g = slot / 12, nt = slot - g * 12;  // g in [0,8)
  int mt = g * 8 + xcd;
  int m0 = mt << 7, n0 = nt << 7;
  int t = threadIdx.x, lane = t & 63, w = t >> 6;
  int mw = w >> 1, nw = w & 1;
  int q4 = lane >> 4, c16 = lane & 15;
  __shared__ __align__(16) char smem[36864];
  bf16* As = (bf16*)smem;            // [2][128][32] key-swizzled via global src
  bf16* Bs = (bf16*)(smem + 16384);  // [2][128][32]

  int goff[2], ldsoff[2];
#pragma unroll
  for (int p = 0; p < 2; ++p) {
    int idx = p * 256 + t;           // 512 slots = 128 rows x 4 chunks
    int row = idx >> 2, s0 = idx & 3;
    int key = (row + (row >> 2)) & 3;
    goff[p] = row * C + ((s0 ^ key) * 8);
    ldsoff[p] = idx * 8;             // linear LDS dest (gll16 requirement)
  }

  f32x4 acc[4][4];
#pragma unroll
  for (int mi = 0; mi < 4; ++mi)
#pragma unroll
    for (int ni = 0; ni < 4; ++ni) acc[mi][ni] = (f32x4){0.f, 0.f, 0.f, 0.f};

  const bf16* ap = hn + (size_t)m0 * C;
  const bf16* bp = wq + (size_t)n0 * C;

  // prologue: stage k-step 0 into buf 0
#pragma unroll
  for (int p = 0; p < 2; ++p) {
    gll16(ap + goff[p], As + ldsoff[p]);
    gll16(bp + goff[p], Bs + ldsoff[p]);
  }
  __syncthreads();

  for (int it = 0; it < 16; ++it) {
    int cur = it & 1;
    if (it < 15) {                   // issue next step's stage FIRST (flies over compute)
      int k1 = (it + 1) * 32;
#pragma unroll
      for (int p = 0; p < 2; ++p) {
        gll16(ap + k1 + goff[p], As + (cur ^ 1) * 4096 + ldsoff[p]);
        gll16(bp + k1 + goff[p], Bs + (cur ^ 1) * 4096 + ldsoff[p]);
      }
    }
    const bf16* Ac = As + cur * 4096;
    const bf16* Bc = Bs + cur * 4096;
    bf16x8 af[4], bfr[4];
#pragma unroll
    for (int mi = 0; mi < 4; ++mi) {
      int row = mw * 64 + mi * 16 + c16;
      int key = (row + (row >> 2)) & 3;
      af[mi] = ld8(Ac + row * 32 + ((q4 ^ key) * 8));
    }
#pragma unroll
    for (int ni = 0; ni < 4; ++ni) {
      int row = nw * 64 + ni * 16 + c16;
      int key = (row + (row >> 2)) & 3;
      bfr[ni] = ld8(Bc + row * 32 + ((q4 ^ key) * 8));
    }
#pragma unroll
    for (int mi = 0; mi < 4; ++mi)
#pragma unroll
      for (int ni = 0; ni < 4; ++ni)
        acc[mi][ni] = __builtin_amdgcn_mfma_f32_16x16x32_bf16(af[mi], bfr[ni], acc[mi][ni], 0, 0, 0);
    // full drain at iter END: prefetch had the compute phase to land; lockstep preserved
    __syncthreads();
  }

  int i = nt >> 2;                    // 0=q 1=k 2=v
  int h = ((nt & 3) << 1) + nw;
  int b = m0 >> 11;
  int l0 = (m0 & (L - 1)) + mw * 64;
  float bias[4];
#pragma unroll
  for (int ni = 0; ni < 4; ++ni) bias[ni] = bq[n0 + nw * 64 + ni * 16 + c16];
  bf16* Os = (bf16*)(smem + w * 9216);  // per-wave [64][72], aliases As/Bs (dead now)

  if (i == 2) {
#pragma unroll
    for (int mi = 0; mi < 4; ++mi)
#pragma unroll
      for (int ni = 0; ni < 4; ++ni) {
        bf16x4 pk;
#pragma unroll
        for (int r = 0; r < 4; ++r) pk[r] = (bf16)(acc[mi][ni][r] + bias[ni]);
        *(bf16x4*)&Os[(ni * 16 + c16) * 72 + mi * 16 + q4 * 4] = pk;
      }
    __syncthreads();
    const bf16* src = Os + lane * 72;
    bf16* dst = vg + ((size_t)((b * H + h) * DH + lane)) * L + l0;
#pragma unroll
    for (int s = 0; s < 8; ++s)
      *(uint4*)(dst + s * 8) = *(const uint4*)(src + s * 8);
  } else {
    float sc = (i == 0) ? QSCALE : 1.0f;
#pragma unroll
    for (int mi = 0; mi < 4; ++mi)
#pragma unroll
      for (int ni = 0; ni < 4; ++ni)
#pragma unroll
        for (int r = 0; r < 4; ++r)
          Os[(mi * 16 + q4 * 4 + r) * 72 + ni * 16 + c16] = (bf16)((acc[mi][ni][r] + bias[ni]) * sc);
    __syncthreads();
    bf16* dst0 = (i == 0) ? qg : kg;
    const bf16* src = Os + lane * 72;
    bf16* dst = dst0 + ((size_t)((b * H + h) * L + l0 + lane)) * DH;
#pragma unroll
    for (int s = 0; s < 8; ++s)
      *(uint4*)(dst + s * 8) = *(const uint4*)(src + s * 8);
  }
}

// ---------------- flash attention v14 (frozen): permlane P-transpose, no Ps LDS ----------------
// PLATEAU (parked): v6 / v12 / v14 all 53.5±0.5; v14 now 51.3 µs, bank-conflicts 0,
// FETCH 12.3 MB. Residual = serial S->softmax->PV chain in lockstep convoy.
__global__ __launch_bounds__(256, 4) void k_attn(const bf16* __restrict__ qg,
                                                 const bf16* __restrict__ kg,
                                                 const bf16* __restrict__ vt,
                                                 bf16* __restrict__ opart,
                                                 float* __restrict__ lsum) {
  int i0 = blockIdx.x;
  int x = i0 & 7, slot = i0 >> 3;
  int bh = ((slot >> 5) << 3) + x;   // (slot/32)*8 + x  ∈ [0,32)
  int inner = slot & 31;
  int js = inner >> 4;
  int qt = inner & 15;
  int t = threadIdx.x, lane = t & 63, w = t >> 6;  // w: 0..3
  int q4 = lane >> 4, c16 = lane & 15;
  __shared__ __align__(16) bf16 Ks[2][64][64];    // 16B-chunk XOR swizzled, double-buffered
  __shared__ __align__(16) bf16 Vts[2][64][64];   // [d][j], same swizzle, double-buffered
  const bf16* qptr  = qg + ((size_t)bh * L + qt * 128 + w * 32) * DH;
  const bf16* kptr  = kg + (size_t)bh * L * DH;
  const bf16* vtptr = vt + (size_t)bh * DH * L;

  int ksoff[2], vsoff[2];
#pragma unroll
  for (int p = 0; p < 2; ++p) {
    int ci = p * 256 + w * 64 + lane;
    int row = ci >> 3, s0 = ci & 7;
    int ch = s0 ^ (row & 7);
    ksoff[p] = row * DH + ch * 8;
    vsoff[p] = row * L + ch * 8;
  }
  int sw = c16 & 7;

  bf16x8 qf[2][2];
#pragma unroll
  for (int qb = 0; qb < 2; ++qb)
#pragma unroll
    for (int kk2 = 0; kk2 < 2; ++kk2)
      qf[qb][kk2] = ld8(&qptr[(size_t)(qb * 16 + c16) * DH + kk2 * 32 + q4 * 8]);

  f32x4 o_acc[2][4];                 // O^T: col=q(c16), rows d = db*16+q4*4+r
  float l_i[2] = {0.f, 0.f};
#pragma unroll
  for (int qb = 0; qb < 2; ++qb)
#pragma unroll
    for (int db = 0; db < 4; ++db) o_acc[qb][db] = (f32x4){0.f, 0.f, 0.f, 0.f};

  // prologue: stage j-tile 0 into buffer 0, full drain + barrier (iter 0 reads it)
  {
    int j0 = js * 1024;
#pragma unroll
    for (int p = 0; p < 2; ++p) {
      gll16(kptr + (size_t)j0 * DH + ksoff[p], &Ks[0][0][0]  + (p * 4 + w) * 512);
      gll16(vtptr + j0 + vsoff[p],             &Vts[0][0][0] + (p * 4 + w) * 512);
    }
  }
  asm volatile("s_waitcnt vmcnt(0)" ::: "memory");
  __builtin_amdgcn_s_barrier();
  __builtin_amdgcn_sched_barrier(0);

  for (int it = 0; it < 16; ++it) {
    int cur = it & 1;
    // issue next-tile stage FIRST: these loads fly across the whole compute phase
    if (it < 15) {
      int j1 = js * 1024 + (it + 1) * 64;
#pragma unroll
      for (int p = 0; p < 2; ++p) {
        gll16(kptr + (size_t)j1 * DH + ksoff[p], &Ks[cur ^ 1][0][0]  + (p * 4 + w) * 512);
        gll16(vtptr + j1 + vsoff[p],             &Vts[cur ^ 1][0][0] + (p * 4 + w) * 512);
      }
    }
    const bf16* KsC = &Ks[cur][0][0];
    const bf16* VsC = &Vts[cur][0][0];

    // S^T[j][q]: A = K (rows=j), B = Q (rows=q)
    f32x4 s[2][4];
#pragma unroll
    for (int qb = 0; qb < 2; ++qb)
#pragma unroll
      for (int jb = 0; jb < 4; ++jb) s[qb][jb] = (f32x4){0.f, 0.f, 0.f, 0.f};
#pragma unroll
    for (int kk2 = 0; kk2 < 2; ++kk2) {
      int choff = ((kk2 * 4 + q4) ^ sw) * 8;
#pragma unroll
      for (int jb = 0; jb < 4; ++jb) {
        bf16x8 kf = ld8(KsC + (jb * 16 + c16) * 64 + choff);
        s[0][jb] = __builtin_amdgcn_mfma_f32_16x16x32_bf16(kf, qf[0][kk2], s[0][jb], 0, 0, 0);
        s[1][jb] = __builtin_amdgcn_mfma_f32_16x16x32_bf16(kf, qf[1][kk2], s[1][jb], 0, 0, 0);
      }
    }

    // no-max softmax: P = exp2(S)
#pragma unroll
    for (int qb = 0; qb < 2; ++qb) {
      float rs = 0.f;
#pragma unroll
      for (int jb = 0; jb < 4; ++jb)
#pragma unroll
        for (int r = 0; r < 4; ++r) {
          float p_ = __builtin_amdgcn_exp2f(s[qb][jb][r]);
          s[qb][jb][r] = p_;
          rs += p_;
        }
      l_i[qb] += rs;
    }

    // V^T A-fragments (shared across both qb)
    bf16x8 vf[2][4];
#pragma unroll
    for (int kk2 = 0; kk2 < 2; ++kk2) {
      int choff = ((kk2 * 4 + q4) ^ sw) * 8;
#pragma unroll
      for (int db = 0; db < 4; ++db)
        vf[kk2][db] = ld8(VsC + (db * 16 + c16) * 64 + choff);
    }

    // O^T += V^T P^T : P B-fragment via in-register quad-group transpose (VALU, no LDS).
#pragma unroll
    for (int qb = 0; qb < 2; ++qb) {
#pragma unroll
      for (int kk2 = 0; kk2 < 2; ++kk2) {
        unsigned a = pack_bf16(s[qb][2 * kk2][0],     s[qb][2 * kk2][1]);
        unsigned b = pack_bf16(s[qb][2 * kk2][2],     s[qb][2 * kk2][3]);
        unsigned c = pack_bf16(s[qb][2 * kk2 + 1][0], s[qb][2 * kk2 + 1][1]);
        unsigned d = pack_bf16(s[qb][2 * kk2 + 1][2], s[qb][2 * kk2 + 1][3]);
        asm("v_permlane32_swap_b32 %0, %1" : "+v"(a), "+v"(c));
        asm("v_permlane32_swap_b32 %0, %1" : "+v"(b), "+v"(d));
        asm("v_permlane16_swap_b32 %0, %1" : "+v"(a), "+v"(c));
        asm("v_permlane16_swap_b32 %0, %1" : "+v"(b), "+v"(d));
        uint4 pu = {a, b, c, d};     // pf u32s: j {+0,+1},{+2,+3},{+4,+5},{+6,+7}
        bf16x8 pf = __builtin_bit_cast(bf16x8, pu);
#pragma unroll
        for (int db = 0; db < 4; ++db)
          o_acc[qb][db] = __builtin_amdgcn_mfma_f32_16x16x32_bf16(vf[kk2][db], pf, o_acc[qb][db], 0, 0, 0);
      }
    }

    // full drain at iter END: prefetch had the whole compute phase to land ->
    // wait ~free when L2-resident; global re-sync every iter -> convoy preserved.
    asm volatile("s_waitcnt vmcnt(0)" ::: "memory");
    __builtin_amdgcn_s_barrier();
    __builtin_amdgcn_sched_barrier(0);
  }

  // epilogue: finish l across quads, store raw partials + l
#pragma unroll
  for (int qb = 0; qb < 2; ++qb) {
    float lf = l_i[qb];
    lf += __shfl_xor(lf, 16, 64);
    lf += __shfl_xor(lf, 32, 64);
    int q = qt * 128 + w * 32 + qb * 16 + c16;
    bf16* op = opart + (((size_t)js * BH + bh) * L + q) * DH;
#pragma unroll
    for (int db = 0; db < 4; ++db) {
      uint2 pk;
      pk.x = pack_bf16(o_acc[qb][db][0], o_acc[qb][db][1]);
      pk.y = pack_bf16(o_acc[qb][db][2], o_acc[qb][db][3]);
      *(uint2*)&op[db * 16 + q4 * 4] = pk;
    }
    if (q4 == 0) lsum[((size_t)js * BH + bh) * L + q] = lf;
  }
}

// ---------------- proj GEMM v16: BK=32 rotated reg-staged double-buffer ----------------
// Same rotation as qkv, but reg-staged (the split-j merge forbids gll16): issue opart/wp
// loads for step k+1 at top, compute step k, merge+ds_write after compute (T14
// issue-early/write-late), ONE barrier per iter. Padded stride 40 kills bank conflicts.
// LDS 39.4 KB -> still 4 blocks/CU.
__global__ __launch_bounds__(256) void k_gemm_proj(const bf16* __restrict__ opart,
                                                   const float* __restrict__ lsum,
                                                   const bf16* __restrict__ wp,
                                                   const float* __restrict__ bp,
                                                   const float* __restrict__ x,
                                                   float* __restrict__ out) {
  int i0 = blockIdx.x;               // 1024 = 8 XCD x 128 slots (v15 grouping kept)
  int xcd = i0 & 7, slot = i0 >> 3;
  int nt = slot & 7, g = slot >> 3;  // g in [0,16)
  int mt = g * 8 + xcd;
  int m0 = mt << 6, n0 = nt << 6;
  int t = threadIdx.x;
  int lane = t & 63, w = t >> 6;
  int q4 = lane >> 4, c16 = lane & 15;
  __shared__ __align__(16) bf16 As[2][64][40];   // merged A, dbuf, pad-40
  __shared__ __align__(16) bf16 Bs[2][64][40];   // weights, dbuf, pad-40
  __shared__ float Ot[64][65];
  __shared__ float invs[64][9];
  int b = m0 >> 11, q0 = m0 & (L - 1);
  for (int i = t; i < 512; i += 256) {
    int row = i >> 3, h = i & 7;
    int bhh = b * 8 + h;
    float l0v = lsum[(size_t)bhh * L + q0 + row];
    float l1v = lsum[((size_t)BH + bhh) * L + q0 + row];
    invs[row][h] = 1.0f / (l0v + l1v);
  }
  int srow = t >> 2, s0 = t & 3;     // 64 rows x 4 chunks, 1 slot per thread
  f32x4 acc[4];
#pragma unroll
  for (int nb = 0; nb < 4; ++nb) acc[nb] = (f32x4){0.f, 0.f, 0.f, 0.f};

  // prologue: load step 0 (h=0, lo-half)
  const bf16* a00 = opart + (((size_t)(b * 8 + 0) * L + q0 + srow)) * 64 + s0 * 8;
  uint4 u0 = *(const uint4*)a00;
  uint4 u1 = *(const uint4*)(a00 + (size_t)BH * L * 64);
  bf16x8 wv = ld8(&wp[(size_t)(n0 + srow) * C + s0 * 8]);
  __syncthreads();                   // invs visible
  {
    float inv = invs[srow][0];
    unsigned* p0 = (unsigned*)&u0;
    unsigned* p1 = (unsigned*)&u1;
    uint4 m;
    unsigned* pm = (unsigned*)&m;
#pragma unroll
    for (int k = 0; k < 4; ++k)
      pm[k] = pack_bf16((bf_lo(p0[k]) + bf_lo(p1[k])) * inv,
                        (bf_hi(p0[k]) + bf_hi(p1[k])) * inv);
    *(uint4*)&As[0][srow][s0 * 8] = m;
    *(bf16x8*)&Bs[0][srow][s0 * 8] = wv;
  }
  __syncthreads();

  for (int it = 0; it < 16; ++it) {
    int cur = it & 1;
    uint4 n0u, n1u; bf16x8 nwv;
    if (it < 15) {                   // issue next step's loads FIRST
      int s = it + 1;
      int h = s >> 1;
      const bf16* a0 = opart + (((size_t)(b * 8 + h) * L + q0 + srow)) * 64 + (s & 1) * 32 + s0 * 8;
      n0u = *(const uint4*)a0;
      n1u = *(const uint4*)(a0 + (size_t)BH * L * 64);
      nwv = ld8(&wp[(size_t)(n0 + srow) * C + s * 32 + s0 * 8]);
    }
    // compute step it from buf[cur]
    bf16x8 a = ld8(&As[cur][w * 16 + c16][q4 * 8]);
#pragma unroll
    for (int nb = 0; nb < 4; ++nb) {
      bf16x8 bfr = ld8(&Bs[cur][nb * 16 + c16][q4 * 8]);
      acc[nb] = __builtin_amdgcn_mfma_f32_16x16x32_bf16(a, bfr, acc[nb], 0, 0, 0);
    }
    if (it < 15) {                   // merge + write AFTER compute (loads had time to land)
      float inv = invs[srow][(it + 1) >> 1];
      unsigned* p0 = (unsigned*)&n0u;
      unsigned* p1 = (unsigned*)&n1u;
      uint4 m;
      unsigned* pm = (unsigned*)&m;
#pragma unroll
      for (int k = 0; k < 4; ++k)
        pm[k] = pack_bf16((bf_lo(p0[k]) + bf_lo(p1[k])) * inv,
                          (bf_hi(p0[k]) + bf_hi(p1[k])) * inv);
      *(uint4*)&As[cur ^ 1][srow][s0 * 8] = m;
      *(bf16x8*)&Bs[cur ^ 1][srow][s0 * 8] = nwv;
    }
    __syncthreads();
  }
#pragma unroll
  for (int nb = 0; nb < 4; ++nb)
#pragma unroll
    for (int r = 0; r < 4; ++r)
      Ot[w * 16 + q4 * 4 + r][nb * 16 + c16] = acc[nb][r];
  __syncthreads();
#pragma unroll
  for (int r = 0; r < 16; ++r) {
    int cl = w * 16 + r;
    int c = n0 + cl;
    size_t idx = (size_t)(b * C + c) * L + q0 + lane;
    out[idx] = Ot[lane][cl] + bp[c] + x[idx];
  }
}

extern "C" void kernel_launch(void* const* d_in, const int* in_sizes, int n_in,
                              void* d_out, int out_size, void* d_ws, size_t ws_size,
                              hipStream_t stream) {
  const float* x     = (const float*)d_in[0];
  const float* gamma = (const float*)d_in[1];
  const float* beta  = (const float*)d_in[2];
  const float* wqkv  = (const float*)d_in[3];
  const float* bqkv  = (const float*)d_in[4];
  const float* wproj = (const float*)d_in[5];
  const float* bproj = (const float*)d_in[6];
  float* out = (float*)d_out;
  char* ws = (char*)d_ws;
  bf16* hn  = (bf16*)(ws + OFF_HN);
  bf16* wqb = (bf16*)(ws + OFF_WQKV);
  bf16* wpb = (bf16*)(ws + OFF_WPROJ);
  bf16* qbp = (bf16*)(ws + OFF_Q);
  bf16* kbp = (bf16*)(ws + OFF_K);
  bf16* vbp = (bf16*)(ws + OFF_V);
  bf16* opart = (bf16*)(ws + OFF_OPART);
  float* lsum = (float*)(ws + OFF_ML);

  hipLaunchKernelGGL(k_ln, dim3(B * (L / 32)), dim3(1024), 0, stream,
                     x, gamma, beta, wqkv, wproj, hn, wqb, wpb);
  hipLaunchKernelGGL(k_gemm_qkv, dim3((BL / 128) * (N_QKV / 128)), dim3(256), 0, stream,
                     hn, wqb, bqkv, qbp, kbp, vbp);
  hipLaunchKernelGGL(k_attn, dim3(B * H * (L / 128) * 2), dim3(256), 0, stream,
                     qbp, kbp, vbp, opart, lsum);
  hipLaunchKernelGGL(k_gemm_proj, dim3((BL / 64) * (C / 64)), dim3(256), 0, stream,
                     opart, lsum, wpb, bproj, x, out);
}